// Round 1
// baseline (96.380 us; speedup 1.0000x reference)
//
#include <hip/hip_runtime.h>
#include <math.h>

// MeshfreeKANNet: out[m] = sum_n phi(m,n) * w[n]
//   phi = windowed+normalized softplus(KAN(diff/radius)), cubic window radius 0.06
//   orphan rows (phi_sum < 1e-14) fall back to exp-weighted 8-NN.
// One block of 256 threads per row m. Window==0 for dist>radius, so KAN is
// evaluated only on ~23/2048 active pairs per row.

#define RADIUS 0.06f
#define INV_RADIUS (1.0f / 0.06f)
#define INV_H (4.0f / 3.0f)   // 1/h, h = 0.75

__device__ __forceinline__ float hatf(float x, float g) {
    return fmaxf(1.0f - fabsf(x - g) * INV_H, 0.0f);
}

__global__ __launch_bounds__(256) void meshfree_kan_kernel(
    const float* __restrict__ x, const float* __restrict__ nodes,
    const float* __restrict__ w,
    const float* __restrict__ w1a, const float* __restrict__ w1b,
    const float* __restrict__ w2,
    float* __restrict__ out, int M, int N)
{
    const int m = blockIdx.x;
    if (m >= M) return;
    const int t = threadIdx.x;
    const int lane = t & 63, wave = t >> 6;

    __shared__ float s_w1a[40], s_w1b[40], s_w2[40];
    __shared__ float s_red[8];
    __shared__ float s_bc[2];
    __shared__ unsigned long long s_keys[4];

    if (t < 40)       s_w1a[t]      = w1a[t];
    else if (t < 80)  s_w1b[t - 40] = w1b[t - 40];
    else if (t < 120) s_w2[t - 80]  = w2[t - 80];
    __syncthreads();

    const float x0 = x[2 * m], x1 = x[2 * m + 1];

    float dloc[8];           // per-thread distances for kNN fallback
    float s1 = 0.0f, s2 = 0.0f;

    #pragma unroll
    for (int k = 0; k < 8; ++k) {
        const int n = t + (k << 8);
        float d = 1e30f;
        if (n < N) {
            const float dx = x0 - nodes[2 * n];
            const float dy = x1 - nodes[2 * n + 1];
            d = sqrtf(dx * dx + dy * dy);
            if (d <= RADIUS) {
                // ---- KAN on (dx,dy)/radius ----
                const float u = dx * INV_RADIUS;
                const float v = dy * INV_RADIUS;
                float b0[5], b1[5];
                #pragma unroll
                for (int i = 0; i < 5; ++i) {
                    const float g = -1.5f + 0.75f * (float)i;
                    b0[i] = hatf(u, g);
                    b1[i] = hatf(v, g);
                }
                float o = 0.0f;
                #pragma unroll
                for (int j = 0; j < 8; ++j) {
                    float hj = 0.0f;
                    #pragma unroll
                    for (int i = 0; i < 5; ++i)
                        hj += b0[i] * s_w1a[j * 5 + i] + b1[i] * s_w1b[j * 5 + i];
                    #pragma unroll
                    for (int g = 0; g < 5; ++g) {
                        const float gv = -1.5f + 0.75f * (float)g;
                        o += hatf(hj, gv) * s_w2[j * 5 + g];
                    }
                }
                // stable softplus, matches jax.nn.softplus in fp32
                const float sp = fmaxf(o, 0.0f) + log1pf(expf(-fabsf(o)));
                // cubic window
                const float q = d * INV_RADIUS;
                float win;
                if (q <= 0.5f) win = 2.0f / 3.0f - 4.0f * q * q + 4.0f * q * q * q;
                else           win = 4.0f / 3.0f - 4.0f * q + 4.0f * q * q
                                     - (4.0f / 3.0f) * q * q * q;
                const float pw = sp * win;
                s1 += pw;
                s2 += pw * w[n];
            }
        }
        dloc[k] = d;
    }

    // block reduction of (s1, s2): wave shuffle then LDS combine
    #pragma unroll
    for (int off = 32; off; off >>= 1) {
        s1 += __shfl_down(s1, off);
        s2 += __shfl_down(s2, off);
    }
    if (lane == 0) { s_red[wave] = s1; s_red[4 + wave] = s2; }
    __syncthreads();
    if (t == 0) {
        s_bc[0] = s_red[0] + s_red[1] + s_red[2] + s_red[3];
        s_bc[1] = s_red[4] + s_red[5] + s_red[6] + s_red[7];
    }
    __syncthreads();
    const float phi_sum = s_bc[0];

    if (phi_sum < 1e-14f) {
        // ---- orphan: exp-weighted 8-NN fallback (block-uniform branch) ----
        const float alpha = (float)(20.0 / 0.06);
        unsigned long long last = 0ull;
        float accw = 0.0f, accwv = 0.0f;
        for (int sel = 0; sel < 8; ++sel) {
            unsigned long long best = ~0ull;
            #pragma unroll
            for (int k = 0; k < 8; ++k) {
                const int n = t + (k << 8);
                const unsigned long long key =
                    ((unsigned long long)__float_as_uint(dloc[k]) << 32) |
                    (unsigned)n;
                if (key > last && key < best) best = key;
            }
            // wave min via 2x32-bit shuffles
            #pragma unroll
            for (int off = 32; off; off >>= 1) {
                unsigned lo = (unsigned)best, hi = (unsigned)(best >> 32);
                unsigned olo = __shfl_down(lo, off);
                unsigned ohi = __shfl_down(hi, off);
                unsigned long long other =
                    ((unsigned long long)ohi << 32) | olo;
                if (other < best) best = other;
            }
            if (lane == 0) s_keys[wave] = best;
            __syncthreads();
            unsigned long long bb = s_keys[0];
            if (s_keys[1] < bb) bb = s_keys[1];
            if (s_keys[2] < bb) bb = s_keys[2];
            if (s_keys[3] < bb) bb = s_keys[3];
            last = bb;
            const float dk = __uint_as_float((unsigned)(bb >> 32));
            const int idx = (int)(bb & 0xffffffffu);
            const float wk = expf(-alpha * dk);
            accw += wk;
            accwv += wk * w[idx];
            __syncthreads();   // protect s_keys before next round's write
        }
        if (t == 0) out[m] = accwv / (accw + 1e-18f);
    } else {
        if (t == 0) out[m] = s_bc[1] / (phi_sum + 1e-12f);
    }
}

extern "C" void kernel_launch(void* const* d_in, const int* in_sizes, int n_in,
                              void* d_out, int out_size, void* d_ws, size_t ws_size,
                              hipStream_t stream) {
    const float* x     = (const float*)d_in[0];
    const float* nodes = (const float*)d_in[1];
    const float* w     = (const float*)d_in[2];
    const float* w1a   = (const float*)d_in[3];
    const float* w1b   = (const float*)d_in[4];
    const float* w2    = (const float*)d_in[5];
    const int M = in_sizes[0] / 2;
    const int N = in_sizes[1] / 2;
    float* out = (float*)d_out;
    meshfree_kan_kernel<<<dim3(M), dim3(256), 0, stream>>>(
        x, nodes, w, w1a, w1b, w2, out, M, N);
}

// Round 2
// 75.750 us; speedup vs baseline: 1.2723x; 1.2723x over previous
//
#include <hip/hip_runtime.h>
#include <math.h>

// MeshfreeKANNet: out[m] = sum_n phi(m,n) * w[n]
//   phi = windowed+normalized softplus(KAN(diff/radius)), cubic window radius 0.06
//   orphan rows (phi_sum < 1e-14) fall back to exp-weighted 8-NN.
// One block of 256 threads per row m.
// R2 change: window==0 for dist>radius (~23/2048 active), so phase A does a
// branchless d^2 sweep + ballot-compaction of active indices into LDS; phase B
// evaluates the heavy KAN densely on the ~23 compacted pairs (1 wave-execution
// of the heavy body per block instead of ~16 divergent ones).

#define RADIUS 0.06f
#define INV_RADIUS (1.0f / 0.06f)
#define R2 (0.06f * 0.06f)
#define INV_H (4.0f / 3.0f)   // 1/h, h = 0.75
#define CAP 512               // compaction buffer capacity (expected ~23)

__device__ __forceinline__ float hatf(float x, float g) {
    return fmaxf(1.0f - fabsf(x - g) * INV_H, 0.0f);
}

// softplus(KAN(dx/r, dy/r)) * cubic_window(sqrt(d2)/r)
__device__ __forceinline__ float kan_phi(float dx, float dy, float d2,
                                         const float* __restrict__ s_w1a,
                                         const float* __restrict__ s_w1b,
                                         const float* __restrict__ s_w2) {
    const float u = dx * INV_RADIUS;
    const float v = dy * INV_RADIUS;
    float b0[5], b1[5];
    #pragma unroll
    for (int i = 0; i < 5; ++i) {
        const float g = -1.5f + 0.75f * (float)i;
        b0[i] = hatf(u, g);
        b1[i] = hatf(v, g);
    }
    float o = 0.0f;
    #pragma unroll
    for (int j = 0; j < 8; ++j) {
        float hj = 0.0f;
        #pragma unroll
        for (int i = 0; i < 5; ++i)
            hj += b0[i] * s_w1a[j * 5 + i] + b1[i] * s_w1b[j * 5 + i];
        #pragma unroll
        for (int g = 0; g < 5; ++g) {
            const float gv = -1.5f + 0.75f * (float)g;
            o += hatf(hj, gv) * s_w2[j * 5 + g];
        }
    }
    // stable softplus (matches jax.nn.softplus in fp32)
    const float sp = fmaxf(o, 0.0f) + log1pf(expf(-fabsf(o)));
    // cubic window on q = d/r
    const float q = sqrtf(d2) * INV_RADIUS;
    float win;
    if (q <= 0.5f) win = 2.0f / 3.0f - 4.0f * q * q + 4.0f * q * q * q;
    else           win = 4.0f / 3.0f - 4.0f * q + 4.0f * q * q
                         - (4.0f / 3.0f) * q * q * q;
    return sp * win;
}

__global__ __launch_bounds__(256) void meshfree_kan_kernel(
    const float* __restrict__ x, const float* __restrict__ nodes,
    const float* __restrict__ w,
    const float* __restrict__ w1a, const float* __restrict__ w1b,
    const float* __restrict__ w2,
    float* __restrict__ out, int M, int N)
{
    const int m = blockIdx.x;
    if (m >= M) return;
    const int t = threadIdx.x;
    const int lane = t & 63, wave = t >> 6;
    const float2* __restrict__ nodes2 = (const float2*)nodes;

    __shared__ float s_w1a[40], s_w1b[40], s_w2[40];
    __shared__ float s_red[8];
    __shared__ float s_bc[2];
    __shared__ unsigned long long s_keys[4];
    __shared__ int s_idx[CAP];
    __shared__ int s_cnt;

    if (t == 0) s_cnt = 0;
    if (t < 40)       s_w1a[t]      = w1a[t];
    else if (t < 80)  s_w1b[t - 40] = w1b[t - 40];
    else if (t < 120) s_w2[t - 80]  = w2[t - 80];
    __syncthreads();

    const float x0 = x[2 * m], x1 = x[2 * m + 1];

    // ---- Phase A: branchless d^2 sweep (8 nodes/thread), compaction ----
    float2 nd[8];
    #pragma unroll
    for (int k = 0; k < 8; ++k) {
        const int n = t + (k << 8);
        nd[k] = (n < N) ? nodes2[n] : make_float2(1e15f, 1e15f);
    }
    float dloc[8];   // squared distances, kept for kNN fallback
    float s1 = 0.0f, s2 = 0.0f;
    #pragma unroll
    for (int k = 0; k < 8; ++k) {
        const int n = t + (k << 8);
        const float dx = x0 - nd[k].x;
        const float dy = x1 - nd[k].y;
        const float d2 = fmaf(dx, dx, dy * dy);
        dloc[k] = d2;
        const bool active = (d2 <= R2) && (n < N);
        const unsigned long long mask = __ballot(active);
        if (mask) {                       // wave-uniform
            int base;
            if (lane == 0) base = atomicAdd(&s_cnt, __popcll(mask));
            base = __shfl(base, 0);
            if (active) {
                const int p = base + __popcll(mask & ((1ull << lane) - 1));
                if (p < CAP) {
                    s_idx[p] = n;
                } else {
                    // overflow (never with uniform data): evaluate inline
                    const float pw = kan_phi(dx, dy, d2, s_w1a, s_w1b, s_w2);
                    s1 += pw;
                    s2 += pw * w[n];
                }
            }
        }
    }
    __syncthreads();

    // ---- Phase B: dense KAN over compacted pairs (~23 of them) ----
    const int cnt = min(s_cnt, CAP);
    for (int i = t; i < cnt; i += 256) {
        const int n = s_idx[i];
        const float2 p = nodes2[n];       // L1-hot
        const float dx = x0 - p.x;
        const float dy = x1 - p.y;
        const float d2 = fmaf(dx, dx, dy * dy);
        const float pw = kan_phi(dx, dy, d2, s_w1a, s_w1b, s_w2);
        s1 += pw;
        s2 += pw * w[n];
    }

    // ---- block reduction of (s1, s2) ----
    #pragma unroll
    for (int off = 32; off; off >>= 1) {
        s1 += __shfl_down(s1, off);
        s2 += __shfl_down(s2, off);
    }
    if (lane == 0) { s_red[wave] = s1; s_red[4 + wave] = s2; }
    __syncthreads();
    if (t == 0) {
        s_bc[0] = s_red[0] + s_red[1] + s_red[2] + s_red[3];
        s_bc[1] = s_red[4] + s_red[5] + s_red[6] + s_red[7];
    }
    __syncthreads();
    const float phi_sum = s_bc[0];

    if (phi_sum < 1e-14f) {
        // ---- orphan: exp-weighted 8-NN fallback (block-uniform, rare) ----
        // Keys order by d^2 (monotone in d). Safe: fallback only runs when no
        // node is within radius, so all d2 >= R2 > 0 and key > 0 always.
        const float alpha = (float)(20.0 / 0.06);
        unsigned long long last = 0ull;
        float accw = 0.0f, accwv = 0.0f;
        for (int sel = 0; sel < 8; ++sel) {
            unsigned long long best = ~0ull;
            #pragma unroll
            for (int k = 0; k < 8; ++k) {
                const int n = t + (k << 8);
                const unsigned long long key =
                    ((unsigned long long)__float_as_uint(dloc[k]) << 32) |
                    (unsigned)n;
                if (key > last && key < best) best = key;
            }
            #pragma unroll
            for (int off = 32; off; off >>= 1) {
                unsigned lo = (unsigned)best, hi = (unsigned)(best >> 32);
                unsigned olo = __shfl_down(lo, off);
                unsigned ohi = __shfl_down(hi, off);
                unsigned long long other =
                    ((unsigned long long)ohi << 32) | olo;
                if (other < best) best = other;
            }
            if (lane == 0) s_keys[wave] = best;
            __syncthreads();
            unsigned long long bb = s_keys[0];
            if (s_keys[1] < bb) bb = s_keys[1];
            if (s_keys[2] < bb) bb = s_keys[2];
            if (s_keys[3] < bb) bb = s_keys[3];
            last = bb;
            const float dk = sqrtf(__uint_as_float((unsigned)(bb >> 32)));
            const int idx = (int)(bb & 0xffffffffu);
            const float wk = expf(-alpha * dk);
            accw += wk;
            accwv += wk * w[idx];
            __syncthreads();
        }
        if (t == 0) out[m] = accwv / (accw + 1e-18f);
    } else {
        if (t == 0) out[m] = s_bc[1] / (phi_sum + 1e-12f);
    }
}

extern "C" void kernel_launch(void* const* d_in, const int* in_sizes, int n_in,
                              void* d_out, int out_size, void* d_ws, size_t ws_size,
                              hipStream_t stream) {
    const float* x     = (const float*)d_in[0];
    const float* nodes = (const float*)d_in[1];
    const float* w     = (const float*)d_in[2];
    const float* w1a   = (const float*)d_in[3];
    const float* w1b   = (const float*)d_in[4];
    const float* w2    = (const float*)d_in[5];
    const int M = in_sizes[0] / 2;
    const int N = in_sizes[1] / 2;
    float* out = (float*)d_out;
    meshfree_kan_kernel<<<dim3(M), dim3(256), 0, stream>>>(
        x, nodes, w, w1a, w1b, w2, out, M, N);
}